// Round 10
// baseline (112.175 us; speedup 1.0000x reference)
//
#include <hip/hip_runtime.h>

// SpectralConv2D: out[f,row,col,q] = relu( sum_{k=0..8} Lambda[phi] * Yflat[phi*128+q] )
// phi = (3*row+block)*378 + (3*col+j);  Yflat is flattened (C=128,R=378,S=378) with
// Y[c,r,s] = raw[c*16384 + (r/3+r%3)*128 + (s/3+s%3)];  broadcast over f=0..63.
// Fused single-pass, LPB=18 (9KB per-plane contiguous runs), nontemporal stores,
// default dispatch order (round-robin XCD = cooperative sequential streams).

#define L_TOT 15876            // 126*126
#define L32   (L_TOT * 32)     // f4 per filter plane
#define LPB   18               // l-rows per block; 15876/18 = 882 exactly
#define NWG   (L_TOT / LPB)    // 882
#define FCH   (LPB * 128 / 4)  // f4 per filter chunk = 576

typedef float f4 __attribute__((ext_vector_type(4)));

__global__ __launch_bounds__(256) void spectral_kernel(
    const float* __restrict__ x, const float* __restrict__ lam,
    float* __restrict__ out)
{
    __shared__ float s[LPB * 128];     // 9 KB
    const int t  = threadIdx.x;        // 0..255
    const int q  = t & 127;
    const int l0 = blockIdx.x * LPB;

    // Each thread computes 9 rows: li = (t>>7), (t>>7)+2, ..., (t>>7)+16.
#pragma unroll
    for (int li = (t >> 7); li < LPB; li += 2) {
        const int l = l0 + li;
        const int row = l / 126;
        const int col = l - row * 126;
        float acc = 0.0f;
#pragma unroll
        for (int b3 = 0; b3 < 3; ++b3) {
#pragma unroll
            for (int j = 0; j < 3; ++j) {
                const unsigned phi = (unsigned)((3 * row + b3) * 378 + 3 * col + j);
                const unsigned n   = phi * 128u + (unsigned)q;  // fits u32
                const unsigned c   = n / 142884u;               // 378*378
                const unsigned rem = n - c * 142884u;
                const unsigned r   = rem / 378u;
                const unsigned ss  = rem - r * 378u;
                const unsigned src = c * 16384u + (r / 3u + r % 3u) * 128u + (ss / 3u + ss % 3u);
                acc = fmaf(x[src], lam[phi], acc);
            }
        }
        s[li * 128 + q] = fmaxf(acc, 0.0f);
    }
    __syncthreads();

    // Broadcast to 64 filter planes: emit each plane's full 9KB run back-to-back
    // (f-major flat index), nontemporal f4 stores.
    const f4* s4 = (const f4*)s;       // FCH f4 covering the LPB rows
    f4* out4 = (f4*)out;
    const size_t lbase = (size_t)l0 * 32;
#pragma unroll
    for (int i = 0; i < FCH * 64 / 256; ++i) {   // 144 iterations
        const int idx = i * 256 + t;             // 0..36863
        const int f = idx / FCH;                 // filter 0..63 (const div -> mul)
        const int v = idx - f * FCH;             // f4 index within chunk
        __builtin_nontemporal_store(s4[v], &out4[(size_t)f * L32 + lbase + v]);
    }
}

extern "C" void kernel_launch(void* const* d_in, const int* in_sizes, int n_in,
                              void* d_out, int out_size, void* d_ws, size_t ws_size,
                              hipStream_t stream) {
    const float* x   = (const float*)d_in[0];   // (1,128,128,128) f32
    const float* lam = (const float*)d_in[1];   // (1, 142884) f32
    float* out = (float*)d_out;                 // (64,126,126,128) f32

    spectral_kernel<<<NWG, 256, 0, stream>>>(x, lam, out);
}

// Round 11
// 101.541 us; speedup vs baseline: 1.1047x; 1.1047x over previous
//
#include <hip/hip_runtime.h>

// SpectralConv2D: out[f,row,col,q] = relu( sum_{k=0..8} Lambda[phi] * Yflat[phi*128+q] )
// phi = (3*row+block)*378 + (3*col+j);  Yflat is flattened (C=128,R=378,S=378) with
// Y[c,r,s] = raw[c*16384 + (r/3+r%3)*128 + (s/3+s%3)];  broadcast over f=0..63.
// R4 store-address pattern (LPB=4, plane pairs 2j,2j+1, nt stores, default
// dispatch) but register-resident drain: one ds_read_b128 per thread, then a
// pure store+pointer-add chain (no LDS/decode inside the loop).

#define L_TOT 15876   // 126*126
#define L32   (L_TOT * 32)   // f4 per filter plane
#define LPB   4              // l-rows per block

typedef float f4 __attribute__((ext_vector_type(4)));

__global__ __launch_bounds__(256) void spectral_kernel(
    const float* __restrict__ x, const float* __restrict__ lam,
    float* __restrict__ out)
{
    __shared__ float s[LPB * 128];     // 4 rows of 128
    const int t  = threadIdx.x;        // 0..255
    const int l0 = blockIdx.x * LPB;
    const int q  = t & 127;

    // Each thread computes rows (t>>7) and (t>>7)+2.
#pragma unroll
    for (int li = (t >> 7); li < LPB; li += 2) {
        const int l = l0 + li;
        const int row = l / 126;
        const int col = l - row * 126;
        float acc = 0.0f;
#pragma unroll
        for (int b3 = 0; b3 < 3; ++b3) {
#pragma unroll
            for (int j = 0; j < 3; ++j) {
                const unsigned phi = (unsigned)((3 * row + b3) * 378 + 3 * col + j);
                const unsigned n   = phi * 128u + (unsigned)q;  // fits u32
                const unsigned c   = n / 142884u;               // 378*378
                const unsigned rem = n - c * 142884u;
                const unsigned r   = rem / 378u;
                const unsigned ss  = rem - r * 378u;
                const unsigned src = c * 16384u + (r / 3u + r % 3u) * 128u + (ss / 3u + ss % 3u);
                acc = fmaf(x[src], lam[phi], acc);
            }
        }
        s[li * 128 + q] = fmaxf(acc, 0.0f);
    }
    __syncthreads();

    // Register-resident broadcast: thread owns f4 slot v=t&127 of the 2KB chunk;
    // half the threads start at plane 0, half at plane 1; stride 2 planes/iter.
    const f4 val = ((const f4*)s)[t & 127];
    f4* dst = (f4*)out + (size_t)(t >> 7) * L32 + (size_t)l0 * 32 + (t & 127);
#pragma unroll
    for (int j = 0; j < 32; ++j) {
        __builtin_nontemporal_store(val, dst);
        dst += (size_t)2 * L32;            // planes 2j,2j+1 -> 2j+2,2j+3
    }
}

extern "C" void kernel_launch(void* const* d_in, const int* in_sizes, int n_in,
                              void* d_out, int out_size, void* d_ws, size_t ws_size,
                              hipStream_t stream) {
    const float* x   = (const float*)d_in[0];   // (1,128,128,128) f32
    const float* lam = (const float*)d_in[1];   // (1, 142884) f32
    float* out = (float*)d_out;                 // (64,126,126,128) f32

    spectral_kernel<<<L_TOT / LPB, 256, 0, stream>>>(x, lam, out);
}